// Round 20
// baseline (73.806 us; speedup 1.0000x reference)
//
#include <hip/hip_runtime.h>
#include <math.h>

constexpr int C   = 128;
constexpr int HW  = 784;   // 28*28
constexpr int PW  = 32;    // padded row stride (128B aligned); logical cols 0..29
constexpr int PH  = 30;
constexpr int PHW = PW * PH;  // 960

// guaranteed 2-instr L1 tap: v_sub + v_add with abs() source modifier
#define ABS_ACC(acc, d) asm("v_add_f32 %0, %0, abs(%1)" : "+v"(acc) : "v"(d))

// packed fp32 ops (VOP3P, gfx950-valid set: pk_fma/pk_add/pk_mul only)
#define PK_FMA(acc, x, w) asm("v_pk_fma_f32 %0, %1, %2, %0" : "+v"(acc) : "v"(x), "v"(w))
#define PK_ADD(d, x, w)   asm("v_pk_add_f32 %0, %1, %2" : "=v"(d) : "v"(x), "v"(w))

// stage1 map: 784 blocks = 8 regions x 98 tiles of 2x2 px (14x14 per image)
__device__ inline void tile_map2(int wg, int& n, int& h0, int& w0) {
    int region = wg & 7;
    int idx    = wg >> 3;            // 0..97
    n = region >> 1;
    int half = region & 1;
    int th = half * 7 + idx / 14;    // 0..13
    int tw = idx % 14;               // 0..13
    h0 = th * 2;
    w0 = tw * 2;
}

// conv/adder map: 784 blocks = 8 regions x {cohalf(2) x 49 tiles of 2x4 px}
__device__ inline void tile_map4(int wg, int& n, int& h0, int& w0, int& co0) {
    int region = wg & 7;
    int rest   = wg >> 3;            // 0..97
    n = region >> 1;
    int half = region & 1;
    co0 = (rest & 1) * 64;
    int idx = rest >> 1;             // 0..48
    int th = idx / 7, tw = idx % 7;
    h0 = half * 14 + th * 2;
    w0 = tw * 4;
}

// zero pad-border cells adjacent to a 2x2 tile (plane = padded 30x32-stride)
__device__ inline void zero_border2(float* plane, int h0, int w0) {
    if (h0 == 0) {
        plane[w0 + 1] = 0.f; plane[w0 + 2] = 0.f;
        if (w0 == 0)  plane[0]  = 0.f;
        if (w0 == 26) plane[29] = 0.f;
    }
    if (h0 == 26) {
        plane[29 * PW + w0 + 1] = 0.f; plane[29 * PW + w0 + 2] = 0.f;
        if (w0 == 0)  plane[29 * PW]      = 0.f;
        if (w0 == 26) plane[29 * PW + 29] = 0.f;
    }
    if (w0 == 0)  { plane[(h0 + 1) * PW]      = 0.f; plane[(h0 + 2) * PW]      = 0.f; }
    if (w0 == 26) { plane[(h0 + 1) * PW + 29] = 0.f; plane[(h0 + 2) * PW + 29] = 0.f; }
}

// zero pad-border cells adjacent to a 2x4 tile
__device__ inline void zero_border4(float* plane, int h0, int w0) {
    if (h0 == 0) {
#pragma unroll
        for (int c = 0; c < 4; ++c) plane[w0 + 1 + c] = 0.f;
        if (w0 == 0)  plane[0]  = 0.f;
        if (w0 == 24) plane[29] = 0.f;
    }
    if (h0 == 26) {
#pragma unroll
        for (int c = 0; c < 4; ++c) plane[29 * PW + w0 + 1 + c] = 0.f;
        if (w0 == 0)  plane[29 * PW]      = 0.f;
        if (w0 == 24) plane[29 * PW + 29] = 0.f;
    }
    if (w0 == 0)  { plane[(h0 + 1) * PW]      = 0.f; plane[(h0 + 2) * PW]      = 0.f; }
    if (w0 == 24) { plane[(h0 + 1) * PW + 29] = 0.f; plane[(h0 + 2) * PW + 29] = 0.f; }
}

// --- repack: w2 -> [ci][k][co]; a2 -> NEGATED [ci][k][co]; w1/a1 -> [ci][co] ---
__global__ __launch_bounds__(256) void reorder_w(const float* __restrict__ w2,
                                                 const float* __restrict__ a2,
                                                 const float* __restrict__ w1,
                                                 const float* __restrict__ a1,
                                                 float* __restrict__ w2r,
                                                 float* __restrict__ a2r,
                                                 float* __restrict__ w1r,
                                                 float* __restrict__ a1r) {
    int idx = blockIdx.x * 256 + threadIdx.x;
    const int T9 = C * C * 9;
    const int T1 = C * C;
    if (idx < 2 * T9) {
        const float* src = w2; float* dst = w2r; float sgn = 1.f;
        if (idx >= T9) { idx -= T9; src = a2; dst = a2r; sgn = -1.f; }
        int co = idx & 127;
        int r  = idx >> 7;                // ci*9 + k
        int k  = r % 9;
        int ci = r / 9;
        dst[idx] = sgn * src[(co * C + ci) * 9 + k];
        return;
    }
    idx -= 2 * T9;
    if (idx >= 2 * T1) return;
    const float* src = w1; float* dst = w1r;
    if (idx >= T1) { idx -= T1; src = a1; dst = a1r; }
    int co = idx & 127;
    int ci = idx >> 7;
    dst[idx] = src[co * C + ci];          // [ci][co]
}

// --- stage 1: conv1x1 + adder1x1 + BN1 + ReLU -> t1p (padded, borders zeroed) ---
// 784 blocks x 256 threads = co(128) x ciq(2, 64 ci each); 2x2 px per block
__global__ __launch_bounds__(256, 8) void stage1(const float* __restrict__ x,
                                                 const float* __restrict__ w1r,
                                                 const float* __restrict__ a1r,
                                                 const float* __restrict__ g1,
                                                 const float* __restrict__ b1,
                                                 const float* __restrict__ m1,
                                                 const float* __restrict__ v1,
                                                 float* __restrict__ t1p) {
    __shared__ float Xs[C][4];        // [ci][px], px = r*2+c
    __shared__ float Ys[C][4];        // conv output [co][px]
    __shared__ float Rs[C][4];        // ciq=1 partials
    int n, h0, w0;
    tile_map2(blockIdx.x, n, h0, w0);
    int t   = threadIdx.x;
    int co  = t & 127;
    int ciq = t >> 7;                 // 0..1
    int ci0 = ciq * 64;

#pragma unroll
    for (int e = t; e < 512; e += 256) {
        int ci = e >> 2, p = e & 3, r = p >> 1, c = p & 1;
        Xs[ci][p] = x[(n * C + ci) * HW + (h0 + r) * 28 + w0 + c];
    }
    __syncthreads();

    float4 a = make_float4(0.f, 0.f, 0.f, 0.f);
    const float* wp = w1r + co;
#pragma unroll 4
    for (int i = 0; i < 64; ++i) {
        int ci = ci0 + i;
        float wv = wp[ci * C];                                    // coalesced
        float4 xv = *reinterpret_cast<const float4*>(&Xs[ci][0]); // broadcast
        a.x = fmaf(xv.x, wv, a.x);
        a.y = fmaf(xv.y, wv, a.y);
        a.z = fmaf(xv.z, wv, a.z);
        a.w = fmaf(xv.w, wv, a.w);
    }
    if (ciq) *reinterpret_cast<float4*>(&Rs[co][0]) = a;
    __syncthreads();
    if (ciq == 0) {
        float4 r = *reinterpret_cast<const float4*>(&Rs[co][0]);
        a.x += r.x; a.y += r.y; a.z += r.z; a.w += r.w;
        *reinterpret_cast<float4*>(&Ys[co][0]) = a;
    }
    __syncthreads();

    float d0 = 0.f, d1 = 0.f, d2 = 0.f, d3 = 0.f;
    const float* ap = a1r + co;
#pragma unroll 4
    for (int i = 0; i < 64; ++i) {
        int ci = ci0 + i;
        float av = ap[ci * C];
        float4 yv = *reinterpret_cast<const float4*>(&Ys[ci][0]);
        float e0 = yv.x - av; ABS_ACC(d0, e0);
        float e1 = yv.y - av; ABS_ACC(d1, e1);
        float e2 = yv.z - av; ABS_ACC(d2, e2);
        float e3 = yv.w - av; ABS_ACC(d3, e3);
    }
    if (ciq) *reinterpret_cast<float4*>(&Rs[co][0]) = make_float4(d0, d1, d2, d3);
    __syncthreads();
    if (ciq == 0) {
        float4 r = *reinterpret_cast<const float4*>(&Rs[co][0]);
        d0 += r.x; d1 += r.y; d2 += r.z; d3 += r.w;
        float inv = g1[co] / sqrtf(v1[co] + 1e-5f);
        float off = b1[co] - m1[co] * inv;
        float* plane = t1p + (n * C + co) * PHW;
        float* dst = plane + (h0 + 1) * PW + (w0 + 1);
        dst[0]      = fmaxf(-d0 * inv + off, 0.f);
        dst[1]      = fmaxf(-d1 * inv + off, 0.f);
        dst[PW + 0] = fmaxf(-d2 * inv + off, 0.f);
        dst[PW + 1] = fmaxf(-d3 * inv + off, 0.f);
        zero_border2(plane, h0, w0);
    }
}

// --- stage 2: conv3x3 pad 1 -> t2p (padded, borders zeroed) ---
// 784 blocks x 512 threads = co(64) x ciq(8, 16 ci each); 2x4 px per block
// packed-FP32 taps: v_pk_fma_f32 over pixel pairs; Xl even pairs + Xo odd pairs
__global__ __launch_bounds__(512, 6) void conv3x3(const float* __restrict__ t1p,
                                                  const float* __restrict__ w2r,
                                                  float* __restrict__ t2p) {
    __shared__ float Xl[C][4][8];     // 16KB: [ci][halo row][col 0..5 used]
    __shared__ float Xo[C][4][4];     // 8KB:  [ci][halo row][cols 1..4] (odd pairs)
    __shared__ float Rs[7][64][8];    // 14KB
    int n, h0, w0, co0;
    tile_map4(blockIdx.x, n, h0, w0, co0);
    int t   = threadIdx.x;
    int col = t & 63;                 // lane = co within half
    int co  = co0 + col;
    int ciq = t >> 6;                 // 0..7, one wave each
    int ci0 = ciq * 16;

    const float* sp0 = t1p + n * C * PHW + h0 * PW + w0;   // halo origin
#pragma unroll
    for (int e = t; e < 1024; e += 512) {   // Xl: 1024 float4 chunks
        int ci = e >> 3, rh = e & 7, r = rh >> 1, half = rh & 1;
        *reinterpret_cast<float4*>(&Xl[ci][r][half * 4]) =
            *reinterpret_cast<const float4*>(sp0 + ci * PHW + r * PW + half * 4);
    }
    {   // Xo: cols 1..4, one (ci,r) per thread
        int ci = t >> 2, r = t & 3;
        const float* sp = sp0 + ci * PHW + r * PW;
        Xo[ci][r][0] = sp[1]; Xo[ci][r][1] = sp[2];
        Xo[ci][r][2] = sp[3]; Xo[ci][r][3] = sp[4];
    }
    __syncthreads();

    const float* wb = w2r + co;
    double accp[2][2];                // [pr][j] = px pair (2j, 2j+1)
    accp[0][0] = 0.0; accp[0][1] = 0.0; accp[1][0] = 0.0; accp[1][1] = 0.0;

#pragma unroll 2
    for (int i = 0; i < 16; ++i) {
        int ci = ci0 + i;
        const float* wp = wb + ci * 9 * C;
        double wd[9];
#pragma unroll
        for (int k = 0; k < 9; ++k) {
            float wv = wp[k * C];                              // coalesced 256B
            float2 wf = make_float2(wv, wv);
            wd[k] = *reinterpret_cast<double*>(&wf);
        }
#pragma unroll
        for (int r = 0; r < 4; ++r) {
            double e0 = *reinterpret_cast<const double*>(&Xl[ci][r][0]); // (0,1)
            double e1 = *reinterpret_cast<const double*>(&Xl[ci][r][2]); // (2,3)
            double e2 = *reinterpret_cast<const double*>(&Xl[ci][r][4]); // (4,5)
            double o0 = *reinterpret_cast<const double*>(&Xo[ci][r][0]); // (1,2)
            double o1 = *reinterpret_cast<const double*>(&Xo[ci][r][2]); // (3,4)
#pragma unroll
            for (int kh = 0; kh < 3; ++kh) {
                int pr = r - kh;
                if (pr < 0 || pr > 1) continue;
                PK_FMA(accp[pr][0], e0, wd[kh * 3 + 0]);
                PK_FMA(accp[pr][1], e1, wd[kh * 3 + 0]);
                PK_FMA(accp[pr][0], o0, wd[kh * 3 + 1]);
                PK_FMA(accp[pr][1], o1, wd[kh * 3 + 1]);
                PK_FMA(accp[pr][0], e1, wd[kh * 3 + 2]);
                PK_FMA(accp[pr][1], e2, wd[kh * 3 + 2]);
            }
        }
    }

    float2 p00 = *reinterpret_cast<float2*>(&accp[0][0]);
    float2 p01 = *reinterpret_cast<float2*>(&accp[0][1]);
    float2 p10 = *reinterpret_cast<float2*>(&accp[1][0]);
    float2 p11 = *reinterpret_cast<float2*>(&accp[1][1]);
    float acc[2][4] = {{p00.x, p00.y, p01.x, p01.y}, {p10.x, p10.y, p11.x, p11.y}};

    if (ciq) {
        *reinterpret_cast<float4*>(&Rs[ciq - 1][col][0]) = make_float4(acc[0][0], acc[0][1], acc[0][2], acc[0][3]);
        *reinterpret_cast<float4*>(&Rs[ciq - 1][col][4]) = make_float4(acc[1][0], acc[1][1], acc[1][2], acc[1][3]);
    }
    __syncthreads();
    if (ciq == 0) {
#pragma unroll
        for (int q = 0; q < 7; ++q) {
            float4 r0 = *reinterpret_cast<const float4*>(&Rs[q][col][0]);
            float4 r1 = *reinterpret_cast<const float4*>(&Rs[q][col][4]);
            acc[0][0] += r0.x; acc[0][1] += r0.y; acc[0][2] += r0.z; acc[0][3] += r0.w;
            acc[1][0] += r1.x; acc[1][1] += r1.y; acc[1][2] += r1.z; acc[1][3] += r1.w;
        }
        float* plane = t2p + (n * C + co) * PHW;
        float* dst = plane + (h0 + 1) * PW + (w0 + 1);
#pragma unroll
        for (int pc = 0; pc < 4; ++pc) dst[pc]      = acc[0][pc];
#pragma unroll
        for (int pc = 0; pc < 4; ++pc) dst[PW + pc] = acc[1][pc];
        zero_border4(plane, h0, w0);
    }
}

// --- stage 3: adder3x3 + BN2 + ReLU + residual + ReLU -> out ---
// a2r is pre-negated: d = pk_add(x, -w) (1 instr / 2 px), then 2x scalar abs-acc
__global__ __launch_bounds__(512, 6) void adder3x3(const float* __restrict__ t2p,
                                                   const float* __restrict__ a2r,
                                                   const float* __restrict__ x0,
                                                   const float* __restrict__ g2,
                                                   const float* __restrict__ b2,
                                                   const float* __restrict__ m2,
                                                   const float* __restrict__ v2,
                                                   float* __restrict__ out) {
    __shared__ float Xl[C][4][8];
    __shared__ float Xo[C][4][4];
    __shared__ float Rs[7][64][8];
    int n, h0, w0, co0;
    tile_map4(blockIdx.x, n, h0, w0, co0);
    int t   = threadIdx.x;
    int col = t & 63;
    int co  = co0 + col;
    int ciq = t >> 6;                 // 0..7
    int ci0 = ciq * 16;

    const float* sp0 = t2p + n * C * PHW + h0 * PW + w0;
#pragma unroll
    for (int e = t; e < 1024; e += 512) {
        int ci = e >> 3, rh = e & 7, r = rh >> 1, half = rh & 1;
        *reinterpret_cast<float4*>(&Xl[ci][r][half * 4]) =
            *reinterpret_cast<const float4*>(sp0 + ci * PHW + r * PW + half * 4);
    }
    {
        int ci = t >> 2, r = t & 3;
        const float* sp = sp0 + ci * PHW + r * PW;
        Xo[ci][r][0] = sp[1]; Xo[ci][r][1] = sp[2];
        Xo[ci][r][2] = sp[3]; Xo[ci][r][3] = sp[4];
    }
    __syncthreads();

    const float* ab = a2r + co;
    float acc[2][4] = {{0.f,0.f,0.f,0.f},{0.f,0.f,0.f,0.f}};

#pragma unroll 2
    for (int i = 0; i < 16; ++i) {
        int ci = ci0 + i;
        const float* wp = ab + ci * 9 * C;
        double wn[9];                 // (-w,-w) pairs (a2r pre-negated)
#pragma unroll
        for (int k = 0; k < 9; ++k) {
            float wv = wp[k * C];
            float2 wf = make_float2(wv, wv);
            wn[k] = *reinterpret_cast<double*>(&wf);
        }
#pragma unroll
        for (int r = 0; r < 4; ++r) {
            double e0 = *reinterpret_cast<const double*>(&Xl[ci][r][0]);
            double e1 = *reinterpret_cast<const double*>(&Xl[ci][r][2]);
            double e2 = *reinterpret_cast<const double*>(&Xl[ci][r][4]);
            double o0 = *reinterpret_cast<const double*>(&Xo[ci][r][0]);
            double o1 = *reinterpret_cast<const double*>(&Xo[ci][r][2]);
#pragma unroll
            for (int kh = 0; kh < 3; ++kh) {
                int pr = r - kh;
                if (pr < 0 || pr > 1) continue;
                double d; float2 f;
                PK_ADD(d, e0, wn[kh * 3 + 0]); f = *reinterpret_cast<float2*>(&d);
                ABS_ACC(acc[pr][0], f.x); ABS_ACC(acc[pr][1], f.y);
                PK_ADD(d, e1, wn[kh * 3 + 0]); f = *reinterpret_cast<float2*>(&d);
                ABS_ACC(acc[pr][2], f.x); ABS_ACC(acc[pr][3], f.y);
                PK_ADD(d, o0, wn[kh * 3 + 1]); f = *reinterpret_cast<float2*>(&d);
                ABS_ACC(acc[pr][0], f.x); ABS_ACC(acc[pr][1], f.y);
                PK_ADD(d, o1, wn[kh * 3 + 1]); f = *reinterpret_cast<float2*>(&d);
                ABS_ACC(acc[pr][2], f.x); ABS_ACC(acc[pr][3], f.y);
                PK_ADD(d, e1, wn[kh * 3 + 2]); f = *reinterpret_cast<float2*>(&d);
                ABS_ACC(acc[pr][0], f.x); ABS_ACC(acc[pr][1], f.y);
                PK_ADD(d, e2, wn[kh * 3 + 2]); f = *reinterpret_cast<float2*>(&d);
                ABS_ACC(acc[pr][2], f.x); ABS_ACC(acc[pr][3], f.y);
            }
        }
    }

    if (ciq) {
        *reinterpret_cast<float4*>(&Rs[ciq - 1][col][0]) = make_float4(acc[0][0], acc[0][1], acc[0][2], acc[0][3]);
        *reinterpret_cast<float4*>(&Rs[ciq - 1][col][4]) = make_float4(acc[1][0], acc[1][1], acc[1][2], acc[1][3]);
    }
    __syncthreads();
    if (ciq == 0) {
#pragma unroll
        for (int q = 0; q < 7; ++q) {
            float4 r0 = *reinterpret_cast<const float4*>(&Rs[q][col][0]);
            float4 r1 = *reinterpret_cast<const float4*>(&Rs[q][col][4]);
            acc[0][0] += r0.x; acc[0][1] += r0.y; acc[0][2] += r0.z; acc[0][3] += r0.w;
            acc[1][0] += r1.x; acc[1][1] += r1.y; acc[1][2] += r1.z; acc[1][3] += r1.w;
        }
        float inv = g2[co] / sqrtf(v2[co] + 1e-5f);
        float off = b2[co] - m2[co] * inv;
        int base = (n * C + co) * HW + h0 * 28 + w0;
#pragma unroll
        for (int pr = 0; pr < 2; ++pr) {
#pragma unroll
            for (int pc = 0; pc < 4; ++pc) {
                float z = fmaxf(-acc[pr][pc] * inv + off, 0.f);
                z += x0[base + pr * 28 + pc];
                out[base + pr * 28 + pc] = fmaxf(z, 0.f);
            }
        }
    }
}

extern "C" void kernel_launch(void* const* d_in, const int* in_sizes, int n_in,
                              void* d_out, int out_size, void* d_ws, size_t ws_size,
                              hipStream_t stream) {
    const float* x   = (const float*)d_in[0];
    const float* w1  = (const float*)d_in[1];
    const float* a1  = (const float*)d_in[2];
    const float* g1  = (const float*)d_in[3];
    const float* b1  = (const float*)d_in[4];
    const float* m1  = (const float*)d_in[5];
    const float* v1  = (const float*)d_in[6];
    const float* w2  = (const float*)d_in[7];
    const float* a2  = (const float*)d_in[8];
    const float* g2  = (const float*)d_in[9];
    const float* b2  = (const float*)d_in[10];
    const float* m2  = (const float*)d_in[11];
    const float* v2  = (const float*)d_in[12];
    float* out = (float*)d_out;

    float* ws  = (float*)d_ws;
    float* t1p = ws;                       // 4*128*960 = 491520
    float* t2p = t1p + 4 * C * PHW;        // 491520
    float* w2r = t2p + 4 * C * PHW;        // 147456
    float* a2r = w2r + C * C * 9;          // 147456 (negated)
    float* w1r = a2r + C * C * 9;          // 16384
    float* a1r = w1r + C * C;              // 16384

    const int reorder_total = 2 * C * C * 9 + 2 * C * C;
    reorder_w<<<(reorder_total + 255) / 256, 256, 0, stream>>>(w2, a2, w1, a1, w2r, a2r, w1r, a1r);
    stage1<<<784, 256, 0, stream>>>(x, w1r, a1r, g1, b1, m1, v1, t1p);
    conv3x3<<<784, 512, 0, stream>>>(t1p, w2r, t2p);
    adder3x3<<<784, 512, 0, stream>>>(t2p, a2r, x, g2, b2, m2, v2, out);
}

// Round 21
// 69.837 us; speedup vs baseline: 1.0568x; 1.0568x over previous
//
#include <hip/hip_runtime.h>
#include <math.h>

constexpr int C   = 128;
constexpr int HW  = 784;   // 28*28
constexpr int PW  = 32;    // padded row stride (128B aligned); logical cols 0..29
constexpr int PH  = 30;
constexpr int PHW = PW * PH;  // 960

// guaranteed 2-instr L1 tap: v_sub + v_add with abs() source modifier
#define ABS_ACC(acc, d) asm("v_add_f32 %0, %0, abs(%1)" : "+v"(acc) : "v"(d))

// stage1 map: 784 blocks = 8 regions x 98 tiles of 2x2 px (14x14 per image)
__device__ inline void tile_map2(int wg, int& n, int& h0, int& w0) {
    int region = wg & 7;
    int idx    = wg >> 3;            // 0..97
    n = region >> 1;
    int half = region & 1;
    int th = half * 7 + idx / 14;    // 0..13
    int tw = idx % 14;               // 0..13
    h0 = th * 2;
    w0 = tw * 2;
}

// conv/adder map: 784 blocks = n(4) x coq(4, 32 co each) x 49 tiles of 4x4 px
// low 3 bits of wg spread (n, coq-hi) across XCDs
__device__ inline void tile_map16(int wg, int& n, int& h0, int& w0, int& co0) {
    int r3   = wg & 7;
    int unit = wg >> 3;              // 0..97
    n = r3 >> 1;
    int coq = ((r3 & 1) << 1) | (unit & 1);
    co0 = coq * 32;
    int idx = unit >> 1;             // 0..48
    int th = idx / 7, tw = idx % 7;
    h0 = th * 4;
    w0 = tw * 4;
}

// zero pad-border cells adjacent to a 2x2 tile (plane = padded 30x32-stride)
__device__ inline void zero_border2(float* plane, int h0, int w0) {
    if (h0 == 0) {
        plane[w0 + 1] = 0.f; plane[w0 + 2] = 0.f;
        if (w0 == 0)  plane[0]  = 0.f;
        if (w0 == 26) plane[29] = 0.f;
    }
    if (h0 == 26) {
        plane[29 * PW + w0 + 1] = 0.f; plane[29 * PW + w0 + 2] = 0.f;
        if (w0 == 0)  plane[29 * PW]      = 0.f;
        if (w0 == 26) plane[29 * PW + 29] = 0.f;
    }
    if (w0 == 0)  { plane[(h0 + 1) * PW]      = 0.f; plane[(h0 + 2) * PW]      = 0.f; }
    if (w0 == 26) { plane[(h0 + 1) * PW + 29] = 0.f; plane[(h0 + 2) * PW + 29] = 0.f; }
}

// zero pad-border cells adjacent to a 4x4 tile
__device__ inline void zero_border44(float* plane, int h0, int w0) {
    if (h0 == 0) {
#pragma unroll
        for (int c = 0; c < 4; ++c) plane[w0 + 1 + c] = 0.f;
        if (w0 == 0)  plane[0]  = 0.f;
        if (w0 == 24) plane[29] = 0.f;
    }
    if (h0 == 24) {
#pragma unroll
        for (int c = 0; c < 4; ++c) plane[29 * PW + w0 + 1 + c] = 0.f;
        if (w0 == 0)  plane[29 * PW]      = 0.f;
        if (w0 == 24) plane[29 * PW + 29] = 0.f;
    }
    if (w0 == 0) {
#pragma unroll
        for (int r = 0; r < 4; ++r) plane[(h0 + 1 + r) * PW] = 0.f;
    }
    if (w0 == 24) {
#pragma unroll
        for (int r = 0; r < 4; ++r) plane[(h0 + 1 + r) * PW + 29] = 0.f;
    }
}

// --- repack: w2/a2 [co][ci][3][3] -> [ci][k][co]; w1/a1 [co][ci] -> [ci][co] ---
__global__ __launch_bounds__(256) void reorder_w(const float* __restrict__ w2,
                                                 const float* __restrict__ a2,
                                                 const float* __restrict__ w1,
                                                 const float* __restrict__ a1,
                                                 float* __restrict__ w2r,
                                                 float* __restrict__ a2r,
                                                 float* __restrict__ w1r,
                                                 float* __restrict__ a1r) {
    int idx = blockIdx.x * 256 + threadIdx.x;
    const int T9 = C * C * 9;
    const int T1 = C * C;
    if (idx < 2 * T9) {
        const float* src = w2; float* dst = w2r;
        if (idx >= T9) { idx -= T9; src = a2; dst = a2r; }
        int co = idx & 127;
        int r  = idx >> 7;                // ci*9 + k
        int k  = r % 9;
        int ci = r / 9;
        dst[idx] = src[(co * C + ci) * 9 + k];
        return;
    }
    idx -= 2 * T9;
    if (idx >= 2 * T1) return;
    const float* src = w1; float* dst = w1r;
    if (idx >= T1) { idx -= T1; src = a1; dst = a1r; }
    int co = idx & 127;
    int ci = idx >> 7;
    dst[idx] = src[co * C + ci];          // [ci][co]
}

// --- stage 1: conv1x1 + adder1x1 + BN1 + ReLU -> t1p (padded, borders zeroed) ---
// 784 blocks x 256 threads = co(128) x ciq(2, 64 ci each); 2x2 px per block
__global__ __launch_bounds__(256, 8) void stage1(const float* __restrict__ x,
                                                 const float* __restrict__ w1r,
                                                 const float* __restrict__ a1r,
                                                 const float* __restrict__ g1,
                                                 const float* __restrict__ b1,
                                                 const float* __restrict__ m1,
                                                 const float* __restrict__ v1,
                                                 float* __restrict__ t1p) {
    __shared__ float Xs[C][4];        // [ci][px], px = r*2+c
    __shared__ float Ys[C][4];        // conv output [co][px]
    __shared__ float Rs[C][4];        // ciq=1 partials
    int n, h0, w0;
    tile_map2(blockIdx.x, n, h0, w0);
    int t   = threadIdx.x;
    int co  = t & 127;
    int ciq = t >> 7;                 // 0..1
    int ci0 = ciq * 64;

#pragma unroll
    for (int e = t; e < 512; e += 256) {
        int ci = e >> 2, p = e & 3, r = p >> 1, c = p & 1;
        Xs[ci][p] = x[(n * C + ci) * HW + (h0 + r) * 28 + w0 + c];
    }
    __syncthreads();

    float4 a = make_float4(0.f, 0.f, 0.f, 0.f);
    const float* wp = w1r + co;
#pragma unroll 4
    for (int i = 0; i < 64; ++i) {
        int ci = ci0 + i;
        float wv = wp[ci * C];                                    // coalesced
        float4 xv = *reinterpret_cast<const float4*>(&Xs[ci][0]); // broadcast
        a.x = fmaf(xv.x, wv, a.x);
        a.y = fmaf(xv.y, wv, a.y);
        a.z = fmaf(xv.z, wv, a.z);
        a.w = fmaf(xv.w, wv, a.w);
    }
    if (ciq) *reinterpret_cast<float4*>(&Rs[co][0]) = a;
    __syncthreads();
    if (ciq == 0) {
        float4 r = *reinterpret_cast<const float4*>(&Rs[co][0]);
        a.x += r.x; a.y += r.y; a.z += r.z; a.w += r.w;
        *reinterpret_cast<float4*>(&Ys[co][0]) = a;
    }
    __syncthreads();

    float d0 = 0.f, d1 = 0.f, d2 = 0.f, d3 = 0.f;
    const float* ap = a1r + co;
#pragma unroll 4
    for (int i = 0; i < 64; ++i) {
        int ci = ci0 + i;
        float av = ap[ci * C];
        float4 yv = *reinterpret_cast<const float4*>(&Ys[ci][0]);
        float e0 = yv.x - av; ABS_ACC(d0, e0);
        float e1 = yv.y - av; ABS_ACC(d1, e1);
        float e2 = yv.z - av; ABS_ACC(d2, e2);
        float e3 = yv.w - av; ABS_ACC(d3, e3);
    }
    if (ciq) *reinterpret_cast<float4*>(&Rs[co][0]) = make_float4(d0, d1, d2, d3);
    __syncthreads();
    if (ciq == 0) {
        float4 r = *reinterpret_cast<const float4*>(&Rs[co][0]);
        d0 += r.x; d1 += r.y; d2 += r.z; d3 += r.w;
        float inv = g1[co] / sqrtf(v1[co] + 1e-5f);
        float off = b1[co] - m1[co] * inv;
        float* plane = t1p + (n * C + co) * PHW;
        float* dst = plane + (h0 + 1) * PW + (w0 + 1);
        dst[0]      = fmaxf(-d0 * inv + off, 0.f);
        dst[1]      = fmaxf(-d1 * inv + off, 0.f);
        dst[PW + 0] = fmaxf(-d2 * inv + off, 0.f);
        dst[PW + 1] = fmaxf(-d3 * inv + off, 0.f);
        zero_border2(plane, h0, w0);
    }
}

// --- stage 2: conv3x3 pad 1 -> t2p (padded, borders zeroed) ---
// 784 blocks x 256 threads = co(32) x ciq(8, 16 ci each); 4x4 px per block
// x-halo (6x6) staged in LDS; 16 accumulators/thread amortize per-ci overhead
__global__ __launch_bounds__(256, 4) void conv3x3(const float* __restrict__ t1p,
                                                  const float* __restrict__ w2r,
                                                  float* __restrict__ t2p) {
    __shared__ float Xl[C][6][8];     // 24KB: [ci][halo row][col 0..5 used]
    __shared__ float Rs[7][32][16];   // 14KB
    int n, h0, w0, co0;
    tile_map16(blockIdx.x, n, h0, w0, co0);
    int t   = threadIdx.x;
    int col = t & 31;                 // co within quarter
    int co  = co0 + col;
    int ciq = t >> 5;                 // 0..7
    int ci0 = ciq * 16;

    const float* sp0 = t1p + n * C * PHW + h0 * PW + w0;   // 6x8 halo window
    for (int e = t; e < 1536; e += 256) {   // C*6*2 float4 chunks
        int ci = e / 12, rem = e - ci * 12, r = rem >> 1, hf = rem & 1;
        *reinterpret_cast<float4*>(&Xl[ci][r][hf * 4]) =
            *reinterpret_cast<const float4*>(sp0 + ci * PHW + r * PW + hf * 4);
    }
    __syncthreads();

    const float* wb = w2r + co;
    float acc[16];
#pragma unroll
    for (int j = 0; j < 16; ++j) acc[j] = 0.f;

#pragma unroll 2
    for (int i = 0; i < 16; ++i) {
        int ci = ci0 + i;
        const float* wp = wb + ci * 9 * C;
        float wk[9];
#pragma unroll
        for (int k = 0; k < 9; ++k) wk[k] = wp[k * C];     // coalesced 128B rows
        float xr[6][6];
#pragma unroll
        for (int r = 0; r < 6; ++r) {                      // LDS broadcast
            float4 q = *reinterpret_cast<const float4*>(&Xl[ci][r][0]);
            float2 s = *reinterpret_cast<const float2*>(&Xl[ci][r][4]);
            xr[r][0] = q.x; xr[r][1] = q.y; xr[r][2] = q.z;
            xr[r][3] = q.w; xr[r][4] = s.x; xr[r][5] = s.y;
        }
#pragma unroll
        for (int kh = 0; kh < 3; ++kh)
#pragma unroll
            for (int kw = 0; kw < 3; ++kw) {
                float wv = wk[kh * 3 + kw];
#pragma unroll
                for (int pr = 0; pr < 4; ++pr)
#pragma unroll
                    for (int pc = 0; pc < 4; ++pc)
                        acc[pr * 4 + pc] = fmaf(xr[pr + kh][pc + kw], wv, acc[pr * 4 + pc]);
            }
    }

    if (ciq) {
#pragma unroll
        for (int j = 0; j < 4; ++j)
            *reinterpret_cast<float4*>(&Rs[ciq - 1][col][j * 4]) =
                make_float4(acc[j * 4], acc[j * 4 + 1], acc[j * 4 + 2], acc[j * 4 + 3]);
    }
    __syncthreads();
    if (ciq == 0) {
#pragma unroll
        for (int q = 0; q < 7; ++q)
#pragma unroll
            for (int j = 0; j < 16; ++j) acc[j] += Rs[q][col][j];
        float* plane = t2p + (n * C + co) * PHW;
        float* dst = plane + (h0 + 1) * PW + (w0 + 1);
#pragma unroll
        for (int pr = 0; pr < 4; ++pr)
#pragma unroll
            for (int pc = 0; pc < 4; ++pc) dst[pr * PW + pc] = acc[pr * 4 + pc];
        zero_border44(plane, h0, w0);
    }
}

// --- stage 3: adder3x3 + BN2 + ReLU + residual + ReLU -> out ---
// same structure: 4x4 px, co(32) x ciq(8), LDS x-halo, L1 weights
__global__ __launch_bounds__(256, 4) void adder3x3(const float* __restrict__ t2p,
                                                   const float* __restrict__ a2r,
                                                   const float* __restrict__ x0,
                                                   const float* __restrict__ g2,
                                                   const float* __restrict__ b2,
                                                   const float* __restrict__ m2,
                                                   const float* __restrict__ v2,
                                                   float* __restrict__ out) {
    __shared__ float Xl[C][6][8];
    __shared__ float Rs[7][32][16];
    int n, h0, w0, co0;
    tile_map16(blockIdx.x, n, h0, w0, co0);
    int t   = threadIdx.x;
    int col = t & 31;
    int co  = co0 + col;
    int ciq = t >> 5;                 // 0..7
    int ci0 = ciq * 16;

    const float* sp0 = t2p + n * C * PHW + h0 * PW + w0;
    for (int e = t; e < 1536; e += 256) {
        int ci = e / 12, rem = e - ci * 12, r = rem >> 1, hf = rem & 1;
        *reinterpret_cast<float4*>(&Xl[ci][r][hf * 4]) =
            *reinterpret_cast<const float4*>(sp0 + ci * PHW + r * PW + hf * 4);
    }
    __syncthreads();

    const float* ab = a2r + co;
    float acc[16];
#pragma unroll
    for (int j = 0; j < 16; ++j) acc[j] = 0.f;

#pragma unroll 2
    for (int i = 0; i < 16; ++i) {
        int ci = ci0 + i;
        const float* wp = ab + ci * 9 * C;
        float wk[9];
#pragma unroll
        for (int k = 0; k < 9; ++k) wk[k] = wp[k * C];
        float xr[6][6];
#pragma unroll
        for (int r = 0; r < 6; ++r) {
            float4 q = *reinterpret_cast<const float4*>(&Xl[ci][r][0]);
            float2 s = *reinterpret_cast<const float2*>(&Xl[ci][r][4]);
            xr[r][0] = q.x; xr[r][1] = q.y; xr[r][2] = q.z;
            xr[r][3] = q.w; xr[r][4] = s.x; xr[r][5] = s.y;
        }
#pragma unroll
        for (int kh = 0; kh < 3; ++kh)
#pragma unroll
            for (int kw = 0; kw < 3; ++kw) {
                float wv = wk[kh * 3 + kw];
#pragma unroll
                for (int pr = 0; pr < 4; ++pr)
#pragma unroll
                    for (int pc = 0; pc < 4; ++pc) {
                        float e = xr[pr + kh][pc + kw] - wv;
                        ABS_ACC(acc[pr * 4 + pc], e);
                    }
            }
    }

    if (ciq) {
#pragma unroll
        for (int j = 0; j < 4; ++j)
            *reinterpret_cast<float4*>(&Rs[ciq - 1][col][j * 4]) =
                make_float4(acc[j * 4], acc[j * 4 + 1], acc[j * 4 + 2], acc[j * 4 + 3]);
    }
    __syncthreads();
    if (ciq == 0) {
#pragma unroll
        for (int q = 0; q < 7; ++q)
#pragma unroll
            for (int j = 0; j < 16; ++j) acc[j] += Rs[q][col][j];
        float inv = g2[co] / sqrtf(v2[co] + 1e-5f);
        float off = b2[co] - m2[co] * inv;
        int base = (n * C + co) * HW + h0 * 28 + w0;
#pragma unroll
        for (int pr = 0; pr < 4; ++pr)
#pragma unroll
            for (int pc = 0; pc < 4; ++pc) {
                float z = fmaxf(-acc[pr * 4 + pc] * inv + off, 0.f);
                z += x0[base + pr * 28 + pc];
                out[base + pr * 28 + pc] = fmaxf(z, 0.f);
            }
    }
}

extern "C" void kernel_launch(void* const* d_in, const int* in_sizes, int n_in,
                              void* d_out, int out_size, void* d_ws, size_t ws_size,
                              hipStream_t stream) {
    const float* x   = (const float*)d_in[0];
    const float* w1  = (const float*)d_in[1];
    const float* a1  = (const float*)d_in[2];
    const float* g1  = (const float*)d_in[3];
    const float* b1  = (const float*)d_in[4];
    const float* m1  = (const float*)d_in[5];
    const float* v1  = (const float*)d_in[6];
    const float* w2  = (const float*)d_in[7];
    const float* a2  = (const float*)d_in[8];
    const float* g2  = (const float*)d_in[9];
    const float* b2  = (const float*)d_in[10];
    const float* m2  = (const float*)d_in[11];
    const float* v2  = (const float*)d_in[12];
    float* out = (float*)d_out;

    float* ws  = (float*)d_ws;
    float* t1p = ws;                       // 4*128*960 = 491520
    float* t2p = t1p + 4 * C * PHW;        // 491520
    float* w2r = t2p + 4 * C * PHW;        // 147456
    float* a2r = w2r + C * C * 9;          // 147456
    float* w1r = a2r + C * C * 9;          // 16384
    float* a1r = w1r + C * C;              // 16384

    const int reorder_total = 2 * C * C * 9 + 2 * C * C;
    reorder_w<<<(reorder_total + 255) / 256, 256, 0, stream>>>(w2, a2, w1, a1, w2r, a2r, w1r, a1r);
    stage1<<<784, 256, 0, stream>>>(x, w1r, a1r, g1, b1, m1, v1, t1p);
    conv3x3<<<784, 256, 0, stream>>>(t1p, w2r, t2p);
    adder3x3<<<784, 256, 0, stream>>>(t2p, a2r, x, g2, b2, m2, v2, out);
}

// Round 22
// 66.925 us; speedup vs baseline: 1.1028x; 1.0435x over previous
//
#include <hip/hip_runtime.h>
#include <math.h>

constexpr int C   = 128;
constexpr int HW  = 784;   // 28*28
constexpr int PW  = 32;    // padded row stride (128B aligned); logical cols 0..29
constexpr int PH  = 30;
constexpr int PHW = PW * PH;  // 960

// guaranteed 2-instr L1 tap: v_sub + v_add with abs() source modifier
#define ABS_ACC(acc, d) asm("v_add_f32 %0, %0, abs(%1)" : "+v"(acc) : "v"(d))

// stage1 map: 784 blocks = 8 regions x 98 tiles of 2x2 px (14x14 per image)
__device__ inline void tile_map2(int wg, int& n, int& h0, int& w0) {
    int region = wg & 7;
    int idx    = wg >> 3;            // 0..97
    n = region >> 1;
    int half = region & 1;
    int th = half * 7 + idx / 14;    // 0..13
    int tw = idx % 14;               // 0..13
    h0 = th * 2;
    w0 = tw * 2;
}

// conv/adder map: 784 blocks = 8 regions x {cohalf(2) x 49 tiles of 2x4 px}
__device__ inline void tile_map4(int wg, int& n, int& h0, int& w0, int& co0) {
    int region = wg & 7;
    int rest   = wg >> 3;            // 0..97
    n = region >> 1;
    int half = region & 1;
    co0 = (rest & 1) * 64;
    int idx = rest >> 1;             // 0..48
    int th = idx / 7, tw = idx % 7;
    h0 = half * 14 + th * 2;
    w0 = tw * 4;
}

// zero pad-border cells adjacent to a 2x2 tile (plane = padded 30x32-stride)
__device__ inline void zero_border2(float* plane, int h0, int w0) {
    if (h0 == 0) {
        plane[w0 + 1] = 0.f; plane[w0 + 2] = 0.f;
        if (w0 == 0)  plane[0]  = 0.f;
        if (w0 == 26) plane[29] = 0.f;
    }
    if (h0 == 26) {
        plane[29 * PW + w0 + 1] = 0.f; plane[29 * PW + w0 + 2] = 0.f;
        if (w0 == 0)  plane[29 * PW]      = 0.f;
        if (w0 == 26) plane[29 * PW + 29] = 0.f;
    }
    if (w0 == 0)  { plane[(h0 + 1) * PW]      = 0.f; plane[(h0 + 2) * PW]      = 0.f; }
    if (w0 == 26) { plane[(h0 + 1) * PW + 29] = 0.f; plane[(h0 + 2) * PW + 29] = 0.f; }
}

// zero pad-border cells adjacent to a 2x4 tile
__device__ inline void zero_border4(float* plane, int h0, int w0) {
    if (h0 == 0) {
#pragma unroll
        for (int c = 0; c < 4; ++c) plane[w0 + 1 + c] = 0.f;
        if (w0 == 0)  plane[0]  = 0.f;
        if (w0 == 24) plane[29] = 0.f;
    }
    if (h0 == 26) {
#pragma unroll
        for (int c = 0; c < 4; ++c) plane[29 * PW + w0 + 1 + c] = 0.f;
        if (w0 == 0)  plane[29 * PW]      = 0.f;
        if (w0 == 24) plane[29 * PW + 29] = 0.f;
    }
    if (w0 == 0)  { plane[(h0 + 1) * PW]      = 0.f; plane[(h0 + 2) * PW]      = 0.f; }
    if (w0 == 24) { plane[(h0 + 1) * PW + 29] = 0.f; plane[(h0 + 2) * PW + 29] = 0.f; }
}

// --- repack: w2/a2 [co][ci][3][3] -> [ci][k][co]; w1/a1 [co][ci] -> [ci][co] ---
__global__ __launch_bounds__(256) void reorder_w(const float* __restrict__ w2,
                                                 const float* __restrict__ a2,
                                                 const float* __restrict__ w1,
                                                 const float* __restrict__ a1,
                                                 float* __restrict__ w2r,
                                                 float* __restrict__ a2r,
                                                 float* __restrict__ w1r,
                                                 float* __restrict__ a1r) {
    int idx = blockIdx.x * 256 + threadIdx.x;
    const int T9 = C * C * 9;
    const int T1 = C * C;
    if (idx < 2 * T9) {
        const float* src = w2; float* dst = w2r;
        if (idx >= T9) { idx -= T9; src = a2; dst = a2r; }
        int co = idx & 127;
        int r  = idx >> 7;                // ci*9 + k
        int k  = r % 9;
        int ci = r / 9;
        dst[idx] = src[(co * C + ci) * 9 + k];
        return;
    }
    idx -= 2 * T9;
    if (idx >= 2 * T1) return;
    const float* src = w1; float* dst = w1r;
    if (idx >= T1) { idx -= T1; src = a1; dst = a1r; }
    int co = idx & 127;
    int ci = idx >> 7;
    dst[idx] = src[co * C + ci];          // [ci][co]
}

// --- stage 1: conv1x1 + adder1x1 + BN1 + ReLU -> t1p (padded, borders zeroed) ---
// 784 blocks x 256 threads = co(128) x ciq(2, 64 ci each); 2x2 px per block
__global__ __launch_bounds__(256, 8) void stage1(const float* __restrict__ x,
                                                 const float* __restrict__ w1r,
                                                 const float* __restrict__ a1r,
                                                 const float* __restrict__ g1,
                                                 const float* __restrict__ b1,
                                                 const float* __restrict__ m1,
                                                 const float* __restrict__ v1,
                                                 float* __restrict__ t1p) {
    __shared__ float Xs[C][4];        // [ci][px], px = r*2+c
    __shared__ float Ys[C][4];        // conv output [co][px]
    __shared__ float Rs[C][4];        // ciq=1 partials
    int n, h0, w0;
    tile_map2(blockIdx.x, n, h0, w0);
    int t   = threadIdx.x;
    int co  = t & 127;
    int ciq = t >> 7;                 // 0..1
    int ci0 = ciq * 64;

#pragma unroll
    for (int e = t; e < 512; e += 256) {
        int ci = e >> 2, p = e & 3, r = p >> 1, c = p & 1;
        Xs[ci][p] = x[(n * C + ci) * HW + (h0 + r) * 28 + w0 + c];
    }
    __syncthreads();

    float4 a = make_float4(0.f, 0.f, 0.f, 0.f);
    const float* wp = w1r + co;
#pragma unroll 4
    for (int i = 0; i < 64; ++i) {
        int ci = ci0 + i;
        float wv = wp[ci * C];                                    // coalesced
        float4 xv = *reinterpret_cast<const float4*>(&Xs[ci][0]); // broadcast
        a.x = fmaf(xv.x, wv, a.x);
        a.y = fmaf(xv.y, wv, a.y);
        a.z = fmaf(xv.z, wv, a.z);
        a.w = fmaf(xv.w, wv, a.w);
    }
    if (ciq) *reinterpret_cast<float4*>(&Rs[co][0]) = a;
    __syncthreads();
    if (ciq == 0) {
        float4 r = *reinterpret_cast<const float4*>(&Rs[co][0]);
        a.x += r.x; a.y += r.y; a.z += r.z; a.w += r.w;
        *reinterpret_cast<float4*>(&Ys[co][0]) = a;
    }
    __syncthreads();

    float d0 = 0.f, d1 = 0.f, d2 = 0.f, d3 = 0.f;
    const float* ap = a1r + co;
#pragma unroll 4
    for (int i = 0; i < 64; ++i) {
        int ci = ci0 + i;
        float av = ap[ci * C];
        float4 yv = *reinterpret_cast<const float4*>(&Ys[ci][0]);
        float e0 = yv.x - av; ABS_ACC(d0, e0);
        float e1 = yv.y - av; ABS_ACC(d1, e1);
        float e2 = yv.z - av; ABS_ACC(d2, e2);
        float e3 = yv.w - av; ABS_ACC(d3, e3);
    }
    if (ciq) *reinterpret_cast<float4*>(&Rs[co][0]) = make_float4(d0, d1, d2, d3);
    __syncthreads();
    if (ciq == 0) {
        float4 r = *reinterpret_cast<const float4*>(&Rs[co][0]);
        d0 += r.x; d1 += r.y; d2 += r.z; d3 += r.w;
        float inv = g1[co] / sqrtf(v1[co] + 1e-5f);
        float off = b1[co] - m1[co] * inv;
        float* plane = t1p + (n * C + co) * PHW;
        float* dst = plane + (h0 + 1) * PW + (w0 + 1);
        dst[0]      = fmaxf(-d0 * inv + off, 0.f);
        dst[1]      = fmaxf(-d1 * inv + off, 0.f);
        dst[PW + 0] = fmaxf(-d2 * inv + off, 0.f);
        dst[PW + 1] = fmaxf(-d3 * inv + off, 0.f);
        zero_border2(plane, h0, w0);
    }
}

// --- stage 2: conv3x3 pad 1 -> t2p (padded, borders zeroed) ---
// 784 blocks x 512 threads = co(64) x ciq(8, 16 ci each); 2x4 px per block
// x-halo staged once per block into LDS; inner loop = LDS broadcast + weight L1
__global__ __launch_bounds__(512, 6) void conv3x3(const float* __restrict__ t1p,
                                                  const float* __restrict__ w2r,
                                                  float* __restrict__ t2p) {
    __shared__ float Xl[C][4][8];     // 16KB: [ci][halo row][col], cols 0..5 used
    __shared__ float Rs[7][64][8];    // 14KB
    int n, h0, w0, co0;
    tile_map4(blockIdx.x, n, h0, w0, co0);
    int t   = threadIdx.x;
    int col = t & 63;                 // lane = co within half
    int co  = co0 + col;
    int ciq = t >> 6;                 // 0..7, one wave each
    int ci0 = ciq * 16;

    const float* sp0 = t1p + n * C * PHW + h0 * PW + w0;   // halo origin (4x8 window)
#pragma unroll
    for (int e = t; e < 1024; e += 512) {   // 1024 float4 chunks
        int ci = e >> 3, rh = e & 7, r = rh >> 1, half = rh & 1;
        *reinterpret_cast<float4*>(&Xl[ci][r][half * 4]) =
            *reinterpret_cast<const float4*>(sp0 + ci * PHW + r * PW + half * 4);
    }
    __syncthreads();

    const float* wb = w2r + co;
    float acc[2][4] = {{0.f,0.f,0.f,0.f},{0.f,0.f,0.f,0.f}};

#pragma unroll 2
    for (int i = 0; i < 16; ++i) {
        int ci = ci0 + i;
        const float* wp = wb + ci * 9 * C;
        float wk[9];
#pragma unroll
        for (int k = 0; k < 9; ++k) wk[k] = wp[k * C];     // coalesced 256B rows
        float xr[4][6];
#pragma unroll
        for (int r = 0; r < 4; ++r) {                      // LDS broadcast reads
            float4 q = *reinterpret_cast<const float4*>(&Xl[ci][r][0]);
            float2 s = *reinterpret_cast<const float2*>(&Xl[ci][r][4]);
            xr[r][0] = q.x; xr[r][1] = q.y; xr[r][2] = q.z;
            xr[r][3] = q.w; xr[r][4] = s.x; xr[r][5] = s.y;
        }
#pragma unroll
        for (int kh = 0; kh < 3; ++kh)
#pragma unroll
            for (int kw = 0; kw < 3; ++kw) {
                float wv = wk[kh * 3 + kw];
#pragma unroll
                for (int pr = 0; pr < 2; ++pr)
#pragma unroll
                    for (int pc = 0; pc < 4; ++pc)
                        acc[pr][pc] = fmaf(xr[pr + kh][pc + kw], wv, acc[pr][pc]);
            }
    }

    if (ciq) {
        *reinterpret_cast<float4*>(&Rs[ciq - 1][col][0]) = make_float4(acc[0][0], acc[0][1], acc[0][2], acc[0][3]);
        *reinterpret_cast<float4*>(&Rs[ciq - 1][col][4]) = make_float4(acc[1][0], acc[1][1], acc[1][2], acc[1][3]);
    }
    __syncthreads();
    if (ciq == 0) {
#pragma unroll
        for (int q = 0; q < 7; ++q) {
            float4 r0 = *reinterpret_cast<const float4*>(&Rs[q][col][0]);
            float4 r1 = *reinterpret_cast<const float4*>(&Rs[q][col][4]);
            acc[0][0] += r0.x; acc[0][1] += r0.y; acc[0][2] += r0.z; acc[0][3] += r0.w;
            acc[1][0] += r1.x; acc[1][1] += r1.y; acc[1][2] += r1.z; acc[1][3] += r1.w;
        }
        float* plane = t2p + (n * C + co) * PHW;
        float* dst = plane + (h0 + 1) * PW + (w0 + 1);
#pragma unroll
        for (int pc = 0; pc < 4; ++pc) dst[pc]      = acc[0][pc];
#pragma unroll
        for (int pc = 0; pc < 4; ++pc) dst[PW + pc] = acc[1][pc];
        zero_border4(plane, h0, w0);
    }
}

// --- stage 3: adder3x3 + BN2 + ReLU + residual + ReLU -> out ---
// same structure: 512 threads, block-level LDS x-halo, L1 weights
__global__ __launch_bounds__(512, 6) void adder3x3(const float* __restrict__ t2p,
                                                   const float* __restrict__ a2r,
                                                   const float* __restrict__ x0,
                                                   const float* __restrict__ g2,
                                                   const float* __restrict__ b2,
                                                   const float* __restrict__ m2,
                                                   const float* __restrict__ v2,
                                                   float* __restrict__ out) {
    __shared__ float Xl[C][4][8];
    __shared__ float Rs[7][64][8];
    int n, h0, w0, co0;
    tile_map4(blockIdx.x, n, h0, w0, co0);
    int t   = threadIdx.x;
    int col = t & 63;
    int co  = co0 + col;
    int ciq = t >> 6;                 // 0..7
    int ci0 = ciq * 16;

    const float* sp0 = t2p + n * C * PHW + h0 * PW + w0;
#pragma unroll
    for (int e = t; e < 1024; e += 512) {
        int ci = e >> 3, rh = e & 7, r = rh >> 1, half = rh & 1;
        *reinterpret_cast<float4*>(&Xl[ci][r][half * 4]) =
            *reinterpret_cast<const float4*>(sp0 + ci * PHW + r * PW + half * 4);
    }
    __syncthreads();

    const float* ab = a2r + co;
    float acc[2][4] = {{0.f,0.f,0.f,0.f},{0.f,0.f,0.f,0.f}};

#pragma unroll 2
    for (int i = 0; i < 16; ++i) {
        int ci = ci0 + i;
        const float* wp = ab + ci * 9 * C;
        float wk[9];
#pragma unroll
        for (int k = 0; k < 9; ++k) wk[k] = wp[k * C];
        float xr[4][6];
#pragma unroll
        for (int r = 0; r < 4; ++r) {
            float4 q = *reinterpret_cast<const float4*>(&Xl[ci][r][0]);
            float2 s = *reinterpret_cast<const float2*>(&Xl[ci][r][4]);
            xr[r][0] = q.x; xr[r][1] = q.y; xr[r][2] = q.z;
            xr[r][3] = q.w; xr[r][4] = s.x; xr[r][5] = s.y;
        }
#pragma unroll
        for (int kh = 0; kh < 3; ++kh)
#pragma unroll
            for (int kw = 0; kw < 3; ++kw) {
                float wv = wk[kh * 3 + kw];
#pragma unroll
                for (int pr = 0; pr < 2; ++pr)
#pragma unroll
                    for (int pc = 0; pc < 4; ++pc) {
                        float e = xr[pr + kh][pc + kw] - wv;
                        ABS_ACC(acc[pr][pc], e);
                    }
            }
    }

    if (ciq) {
        *reinterpret_cast<float4*>(&Rs[ciq - 1][col][0]) = make_float4(acc[0][0], acc[0][1], acc[0][2], acc[0][3]);
        *reinterpret_cast<float4*>(&Rs[ciq - 1][col][4]) = make_float4(acc[1][0], acc[1][1], acc[1][2], acc[1][3]);
    }
    __syncthreads();
    if (ciq == 0) {
#pragma unroll
        for (int q = 0; q < 7; ++q) {
            float4 r0 = *reinterpret_cast<const float4*>(&Rs[q][col][0]);
            float4 r1 = *reinterpret_cast<const float4*>(&Rs[q][col][4]);
            acc[0][0] += r0.x; acc[0][1] += r0.y; acc[0][2] += r0.z; acc[0][3] += r0.w;
            acc[1][0] += r1.x; acc[1][1] += r1.y; acc[1][2] += r1.z; acc[1][3] += r1.w;
        }
        float inv = g2[co] / sqrtf(v2[co] + 1e-5f);
        float off = b2[co] - m2[co] * inv;
        int base = (n * C + co) * HW + h0 * 28 + w0;
#pragma unroll
        for (int pr = 0; pr < 2; ++pr) {
#pragma unroll
            for (int pc = 0; pc < 4; ++pc) {
                float z = fmaxf(-acc[pr][pc] * inv + off, 0.f);
                z += x0[base + pr * 28 + pc];
                out[base + pr * 28 + pc] = fmaxf(z, 0.f);
            }
        }
    }
}

extern "C" void kernel_launch(void* const* d_in, const int* in_sizes, int n_in,
                              void* d_out, int out_size, void* d_ws, size_t ws_size,
                              hipStream_t stream) {
    const float* x   = (const float*)d_in[0];
    const float* w1  = (const float*)d_in[1];
    const float* a1  = (const float*)d_in[2];
    const float* g1  = (const float*)d_in[3];
    const float* b1  = (const float*)d_in[4];
    const float* m1  = (const float*)d_in[5];
    const float* v1  = (const float*)d_in[6];
    const float* w2  = (const float*)d_in[7];
    const float* a2  = (const float*)d_in[8];
    const float* g2  = (const float*)d_in[9];
    const float* b2  = (const float*)d_in[10];
    const float* m2  = (const float*)d_in[11];
    const float* v2  = (const float*)d_in[12];
    float* out = (float*)d_out;

    float* ws  = (float*)d_ws;
    float* t1p = ws;                       // 4*128*960 = 491520
    float* t2p = t1p + 4 * C * PHW;        // 491520
    float* w2r = t2p + 4 * C * PHW;        // 147456
    float* a2r = w2r + C * C * 9;          // 147456
    float* w1r = a2r + C * C * 9;          // 16384
    float* a1r = w1r + C * C;              // 16384

    const int reorder_total = 2 * C * C * 9 + 2 * C * C;
    reorder_w<<<(reorder_total + 255) / 256, 256, 0, stream>>>(w2, a2, w1, a1, w2r, a2r, w1r, a1r);
    stage1<<<784, 256, 0, stream>>>(x, w1r, a1r, g1, b1, m1, v1, t1p);
    conv3x3<<<784, 512, 0, stream>>>(t1p, w2r, t2p);
    adder3x3<<<784, 512, 0, stream>>>(t2p, a2r, x, g2, b2, m2, v2, out);
}